// Round 3
// baseline (242.081 us; speedup 1.0000x reference)
//
#include <hip/hip_runtime.h>

#define NTOT 50000
#define N0 20000
#define N1 5000
#define N2 1000
#define E0C 320000
#define E1C 80000
#define E2C 16000

__global__ void zero_ints(int* __restrict__ p, int n) {
    int i = blockIdx.x * blockDim.x + threadIdx.x;
    if (i < n) p[i] = 0;
}

// one fused histogram over all 3 graphs (counts: [0,N0)=g0, [N0,N0+N1)=g1, then g2)
__global__ void hist_all(const int* __restrict__ ei0, const int* __restrict__ ei1,
                         const int* __restrict__ ei2, int* __restrict__ counts) {
    int i = blockIdx.x * blockDim.x + threadIdx.x;
    if (i < E0C) {
        atomicAdd(&counts[ei0[E0C + i]], 1);
    } else if (i < E0C + E1C) {
        int j = i - E0C;
        atomicAdd(&counts[N0 + ei1[E1C + j]], 1);
    } else if (i < E0C + E1C + E2C) {
        int j = i - E0C - E1C;
        atomicAdd(&counts[N0 + N1 + ei2[E2C + j]], 1);
    }
}

// one block per graph; shuffle-based single-pass exclusive scan
__global__ __launch_bounds__(1024) void scan_all(
    const int* __restrict__ counts,
    int* __restrict__ offs0, int* __restrict__ cur0,
    int* __restrict__ offs1, int* __restrict__ cur1,
    int* __restrict__ offs2, int* __restrict__ cur2) {
    int g = blockIdx.x;
    int n = (g == 0) ? N0 : (g == 1) ? N1 : N2;
    const int* cnt = counts + ((g == 0) ? 0 : (g == 1) ? N0 : N0 + N1);
    int* offs = (g == 0) ? offs0 : (g == 1) ? offs1 : offs2;
    int* cur  = (g == 0) ? cur0  : (g == 1) ? cur1  : cur2;
    int t = threadIdx.x;
    int chunk = (n + 1023) >> 10;
    int lo = t * chunk;
    int hi = min(lo + chunk, n);
    int s = 0;
    for (int i = lo; i < hi; i++) s += cnt[i];
    int lane = t & 63, wid = t >> 6;
    int v = s;
    for (int d = 1; d < 64; d <<= 1) {
        int u = __shfl_up(v, d, 64);
        if (lane >= d) v += u;
    }
    __shared__ int wsum[16];
    __shared__ int woff[16];
    if (lane == 63) wsum[wid] = v;
    __syncthreads();
    if (t < 16) {
        int wv = wsum[t];
        int iv = wv;
        for (int d = 1; d < 16; d <<= 1) {
            int u = __shfl_up(iv, d, 64);
            if (t >= d) iv += u;
        }
        woff[t] = iv - wv;
    }
    __syncthreads();
    int run = woff[wid] + v - s;
    for (int i = lo; i < hi; i++) {
        offs[i] = run;
        cur[i] = run;
        run += cnt[i];
    }
    if (lo < n && hi == n) offs[n] = run;
}

__global__ void scatter_all(const int* __restrict__ ei0, const int* __restrict__ ei1,
                            const int* __restrict__ ei2,
                            int* __restrict__ cur0, int* __restrict__ cur1, int* __restrict__ cur2,
                            int* __restrict__ ss0, int* __restrict__ ss1, int* __restrict__ ss2) {
    int i = blockIdx.x * blockDim.x + threadIdx.x;
    if (i < E0C) {
        int d = ei0[E0C + i];
        int pos = atomicAdd(&cur0[d], 1);
        ss0[pos] = ei0[i];
    } else if (i < E0C + E1C) {
        int j = i - E0C;
        int d = ei1[E1C + j];
        int pos = atomicAdd(&cur1[d], 1);
        ss1[pos] = ei1[j];
    } else if (i < E0C + E1C + E2C) {
        int j = i - E0C - E1C;
        int d = ei2[E2C + j];
        int pos = atomicAdd(&cur2[d], 1);
        ss2[pos] = ei2[j];
    }
}

// xt0p[n][b][8] = x[b][n_id[n]][0..4] padded to 8 floats
__global__ void gather_kernel(const float* __restrict__ x, const int* __restrict__ n_id,
                              float* __restrict__ xt0p) {
    int idx = blockIdx.x * blockDim.x + threadIdx.x;
    if (idx >= N0 * 16) return;
    int n = idx >> 4, b = idx & 15;
    const float* p = x + (size_t)b * (NTOT * 5) + (size_t)n_id[n] * 5;
    float* q = xt0p + (size_t)n * 128 + b * 8;
    float4 v0 = {p[0], p[1], p[2], p[3]};
    float4 v1 = {p[4], 0.f, 0.f, 0.f};
    *(float4*)q = v0;
    *(float4*)(q + 4) = v1;
}

// SAGE layer 1: wave per dst; lane = es*16+b (4 edge slots x 16 batch).
__global__ __launch_bounds__(256) void sage1_kernel(
    const float* __restrict__ xt0p, const int* __restrict__ offs, const int* __restrict__ ssrc,
    const float* __restrict__ W, const float* __restrict__ bias, float* __restrict__ xt1p) {
    int d = (blockIdx.x * 256 + threadIdx.x) >> 6;
    int q = threadIdx.x & 63;
    int es = q >> 4, b = q & 15;
    const float* ps = xt0p + (size_t)d * 128 + b * 8;
    float4 u0 = *(const float4*)ps;
    float x4 = ps[4];
    float xs[5] = {u0.x, u0.y, u0.z, u0.w, x4};
    float a[5] = {0.f, 0.f, 0.f, 0.f, 0.f};
    int e0 = offs[d], e1 = offs[d + 1];
    for (int e = e0 + es; e < e1; e += 4) {
        int s = ssrc[e];
        const float* p = xt0p + (size_t)s * 128 + b * 8;
        float4 v = *(const float4*)p;
        float v4 = p[4];
        a[0] += v.x; a[1] += v.y; a[2] += v.z; a[3] += v.w; a[4] += v4;
    }
#pragma unroll
    for (int c = 0; c < 5; c++) {
        a[c] += __shfl_xor(a[c], 16, 64);
        a[c] += __shfl_xor(a[c], 32, 64);
    }
    float inv = 1.f / (float)(e1 - e0 + 1);
#pragma unroll
    for (int c = 0; c < 5; c++) a[c] = (a[c] + xs[c]) * inv;
    float o[6];
#pragma unroll
    for (int j = 0; j < 6; j++) {
        float acc = bias[j];
#pragma unroll
        for (int i = 0; i < 5; i++) acc += xs[i] * W[i * 6 + j];
#pragma unroll
        for (int i = 0; i < 5; i++) acc += a[i] * W[(5 + i) * 6 + j];
        o[j] = acc;
    }
    float nrm = 0.f;
#pragma unroll
    for (int j = 0; j < 6; j++) nrm += o[j] * o[j];
    float r = 1.f / fmaxf(sqrtf(nrm), 1e-12f);
    if (es == 0) {
        float* pd = xt1p + (size_t)d * 128 + b * 8;
        float4 w0 = {fmaxf(o[0] * r, 0.f), fmaxf(o[1] * r, 0.f),
                     fmaxf(o[2] * r, 0.f), fmaxf(o[3] * r, 0.f)};
        float2 w1 = {fmaxf(o[4] * r, 0.f), fmaxf(o[5] * r, 0.f)};
        *(float4*)pd = w0;
        *(float2*)(pd + 4) = w1;
    }
}

// SAGE layer 2: wave per dst; lane = es*16+b. Each slot computes 9 of 36 output cols.
__global__ __launch_bounds__(256) void sage2_kernel(
    const float* __restrict__ xt1p, const int* __restrict__ offs, const int* __restrict__ ssrc,
    const float* __restrict__ W, const float* __restrict__ bias, float* __restrict__ xt2) {
    int d = (blockIdx.x * 256 + threadIdx.x) >> 6;
    int q = threadIdx.x & 63;
    int es = q >> 4, b = q & 15;
    const float* ps = xt1p + (size_t)d * 128 + b * 8;
    float4 u0 = *(const float4*)ps;
    float2 u1 = *(const float2*)(ps + 4);
    float xs[6] = {u0.x, u0.y, u0.z, u0.w, u1.x, u1.y};
    float a[6] = {0.f, 0.f, 0.f, 0.f, 0.f, 0.f};
    int e0 = offs[d], e1 = offs[d + 1];
    for (int e = e0 + es; e < e1; e += 4) {
        int s = ssrc[e];
        const float* p = xt1p + (size_t)s * 128 + b * 8;
        float4 v0 = *(const float4*)p;
        float2 v1 = *(const float2*)(p + 4);
        a[0] += v0.x; a[1] += v0.y; a[2] += v0.z; a[3] += v0.w;
        a[4] += v1.x; a[5] += v1.y;
    }
#pragma unroll
    for (int c = 0; c < 6; c++) {
        a[c] += __shfl_xor(a[c], 16, 64);
        a[c] += __shfl_xor(a[c], 32, 64);
    }
    float inv = 1.f / (float)(e1 - e0 + 1);
#pragma unroll
    for (int c = 0; c < 6; c++) a[c] = (a[c] + xs[c]) * inv;
    int j0 = es * 9;
    float o[9];
#pragma unroll
    for (int jj = 0; jj < 9; jj++) {
        int j = j0 + jj;
        float acc = bias[j];
#pragma unroll
        for (int i = 0; i < 6; i++) acc += xs[i] * W[i * 36 + j];
#pragma unroll
        for (int i = 0; i < 6; i++) acc += a[i] * W[(6 + i) * 36 + j];
        o[jj] = acc;
    }
    float pn = 0.f;
#pragma unroll
    for (int jj = 0; jj < 9; jj++) pn += o[jj] * o[jj];
    pn += __shfl_xor(pn, 16, 64);
    pn += __shfl_xor(pn, 32, 64);
    float r = 1.f / fmaxf(sqrtf(pn), 1e-12f);
    float* pd = xt2 + (size_t)d * 576 + b * 36 + j0;
#pragma unroll
    for (int jj = 0; jj < 9; jj++) pd[jj] = fmaxf(o[jj] * r, 0.f);
}

// layer-3 mean aggregation: wave per dst, 2-way unrolled edge loop, writes
// transposed aggT[d][c][b] (via small LDS transpose, coalesced b128 out).
__global__ __launch_bounds__(256) void agg3_kernel(
    const float* __restrict__ xt2, const int* __restrict__ offs, const int* __restrict__ ssrc,
    float* __restrict__ aggT) {
    __shared__ float sT[4][576];
    int t = threadIdx.x;
    int l = t >> 6, q = t & 63;
    int d = blockIdx.x * 4 + l;
    int e0 = offs[d], e1 = offs[d + 1];
    float4 a0 = {0, 0, 0, 0}, a1 = {0, 0, 0, 0}, a2 = {0, 0, 0, 0};
    int e = e0;
    for (; e + 1 < e1; e += 2) {
        int s0 = ssrc[e], s1 = ssrc[e + 1];
        const float4* p0 = (const float4*)(xt2 + (size_t)s0 * 576);
        const float4* p1 = (const float4*)(xt2 + (size_t)s1 * 576);
        float4 v0 = p0[q], w0 = p1[q];
        float4 v1 = p0[q + 64], w1 = p1[q + 64];
        a0.x += v0.x + w0.x; a0.y += v0.y + w0.y; a0.z += v0.z + w0.z; a0.w += v0.w + w0.w;
        a1.x += v1.x + w1.x; a1.y += v1.y + w1.y; a1.z += v1.z + w1.z; a1.w += v1.w + w1.w;
        if (q < 16) {
            float4 v2 = p0[q + 128], w2 = p1[q + 128];
            a2.x += v2.x + w2.x; a2.y += v2.y + w2.y; a2.z += v2.z + w2.z; a2.w += v2.w + w2.w;
        }
    }
    if (e < e1) {
        int s0 = ssrc[e];
        const float4* p0 = (const float4*)(xt2 + (size_t)s0 * 576);
        float4 v0 = p0[q];
        float4 v1 = p0[q + 64];
        a0.x += v0.x; a0.y += v0.y; a0.z += v0.z; a0.w += v0.w;
        a1.x += v1.x; a1.y += v1.y; a1.z += v1.z; a1.w += v1.w;
        if (q < 16) {
            float4 v2 = p0[q + 128];
            a2.x += v2.x; a2.y += v2.y; a2.z += v2.z; a2.w += v2.w;
        }
    }
    float inv = 1.f / fmaxf((float)(e1 - e0), 1.f);
    float av[12] = {a0.x, a0.y, a0.z, a0.w, a1.x, a1.y, a1.z, a1.w, a2.x, a2.y, a2.z, a2.w};
#pragma unroll
    for (int m = 0; m < 3; m++) {
        int chunk = q + 64 * m;
        if (chunk < 144) {
#pragma unroll
            for (int j = 0; j < 4; j++) {
                int el = chunk * 4 + j;      // = b*36 + c
                int bb = el / 36;
                int cc = el - bb * 36;
                sT[l][cc * 16 + bb] = av[m * 4 + j] * inv;
            }
        }
    }
    __syncthreads();
    float4* dst = (float4*)(aggT + (size_t)blockIdx.x * 4 * 576);
    const float4* src = (const float4*)&sT[0][0];
    for (int i = t; i < 576; i += 256) dst[i] = src[i];
}

// layer-3 matmul + fused W4 projection. Wave per dst; W3 in LDS (31KB only);
// aggT rows read as wave-uniform 64B broadcast loads from global.
__global__ __launch_bounds__(256) void matmul3_kernel(
    const float* __restrict__ aggT, const float* __restrict__ W3, const float* __restrict__ b3,
    const float* __restrict__ W4, float* __restrict__ y) {
    __shared__ float sW[36 * 216];
    int t = threadIdx.x;
    const float4* W3v = (const float4*)W3;
    float4* sWv = (float4*)sW;
    for (int i = t; i < 1944; i += 256) sWv[i] = W3v[i];
    __syncthreads();

    int l = t >> 6, q = t & 63;
    int d = blockIdx.x * 4 + l;
    const float* ag = aggT + (size_t)d * 576;
    int qc = (q < 54) ? q : 53;
    int o0 = qc * 4;
    float acc[16][4];
#pragma unroll
    for (int r = 0; r < 16; r++)
#pragma unroll
        for (int c = 0; c < 4; c++) acc[r][c] = 0.f;

#pragma unroll 4
    for (int k = 0; k < 36; k++) {
        float4 w = *(const float4*)&sW[k * 216 + o0];
        const float4* sap = (const float4*)(ag + k * 16);
        float4 s0 = sap[0], s1 = sap[1], s2 = sap[2], s3 = sap[3];
        float sar[16] = {s0.x, s0.y, s0.z, s0.w, s1.x, s1.y, s1.z, s1.w,
                         s2.x, s2.y, s2.z, s2.w, s3.x, s3.y, s3.z, s3.w};
#pragma unroll
        for (int r = 0; r < 16; r++) {
            acc[r][0] = fmaf(sar[r], w.x, acc[r][0]);
            acc[r][1] = fmaf(sar[r], w.y, acc[r][1]);
            acc[r][2] = fmaf(sar[r], w.z, acc[r][2]);
            acc[r][3] = fmaf(sar[r], w.w, acc[r][3]);
        }
    }

    float vals[32];
#pragma unroll
    for (int i = 0; i < 32; i++) vals[i] = 0.f;
    if (q < 54) {
        float4 bb = *(const float4*)&b3[o0];
        float4 w4a = *(const float4*)&W4[o0 * 2];
        float4 w4b = *(const float4*)&W4[o0 * 2 + 4];
        float w40[4] = {w4a.x, w4a.z, w4b.x, w4b.z};
        float w41[4] = {w4a.y, w4a.w, w4b.y, w4b.w};
        float bc[4] = {bb.x, bb.y, bb.z, bb.w};
#pragma unroll
        for (int r = 0; r < 16; r++) {
#pragma unroll
            for (int c = 0; c < 4; c++) {
                float vv = fmaxf(acc[r][c] + bc[c], 0.f);
                vals[r * 2 + 0] = fmaf(vv, w40[c], vals[r * 2 + 0]);
                vals[r * 2 + 1] = fmaf(vv, w41[c], vals[r * 2 + 1]);
            }
        }
    }
#pragma unroll
    for (int i = 0; i < 5; i++) {
        int m = 1 << i;
        int half = 16 >> i;
        bool bit = (q >> i) & 1;
#pragma unroll
        for (int j = 0; j < 16; j++) {
            if (j < half) {
                float lo_ = vals[j], hi_ = vals[j + half];
                float send = bit ? lo_ : hi_;
                float recv = __shfl_xor(send, m, 64);
                vals[j] = (bit ? hi_ : lo_) + recv;
            }
        }
    }
    float tot = vals[0] + __shfl_xor(vals[0], 32, 64);
    if (q < 32) {
        int v = ((q & 1) << 4) | ((q & 2) << 2) | (q & 4) | ((q & 8) >> 2) | ((q & 16) >> 4);
        y[(size_t)d * 32 + v] = tot;   // v = b*2 + k
    }
}

// layer 4: mean-agg of projected y over edges2, + b4. out[b][n][k].
__global__ void final_kernel(const float* __restrict__ y, const int* __restrict__ offs,
                             const int* __restrict__ ssrc, const float* __restrict__ b4,
                             float* __restrict__ out) {
    int idx = blockIdx.x * blockDim.x + threadIdx.x;
    if (idx >= N2 * 16) return;
    int d = idx >> 4, b = idx & 15;
    int e0 = offs[d], e1 = offs[d + 1];
    float s0 = 0.f, s1 = 0.f;
    for (int e = e0; e < e1; e++) {
        int s = ssrc[e];
        const float2 v = *(const float2*)(y + (size_t)s * 32 + b * 2);
        s0 += v.x; s1 += v.y;
    }
    float inv = 1.f / fmaxf((float)(e1 - e0), 1.f);
    out[b * (N2 * 2) + d * 2 + 0] = s0 * inv + b4[0];
    out[b * (N2 * 2) + d * 2 + 1] = s1 * inv + b4[1];
}

extern "C" void kernel_launch(void* const* d_in, const int* in_sizes, int n_in,
                              void* d_out, int out_size, void* d_ws, size_t ws_size,
                              hipStream_t stream) {
    const float* x   = (const float*)d_in[0];
    const int* n_id  = (const int*)d_in[1];
    const int* ei0   = (const int*)d_in[2];
    const int* ei1   = (const int*)d_in[3];
    const int* ei2   = (const int*)d_in[4];
    const float* W1  = (const float*)d_in[5];
    const float* b1  = (const float*)d_in[6];
    const float* W2  = (const float*)d_in[7];
    const float* b2  = (const float*)d_in[8];
    const float* W3  = (const float*)d_in[9];
    const float* b3  = (const float*)d_in[10];
    const float* W4  = (const float*)d_in[11];
    const float* b4  = (const float*)d_in[12];
    float* out = (float*)d_out;

    char* ws = (char*)d_ws;
    size_t off = 0;
    auto alloc = [&](size_t bytes) -> void* {
        void* p = ws + off;
        off += (bytes + 255) & ~(size_t)255;
        return p;
    };
    float* xt0p = (float*)alloc((size_t)N0 * 128 * 4);
    float* xt1p = (float*)alloc((size_t)N0 * 128 * 4);
    float* xt2  = (float*)alloc((size_t)N0 * 576 * 4);
    float* aggT = (float*)alloc((size_t)N1 * 576 * 4);
    float* yb   = (float*)alloc((size_t)N1 * 32 * 4);
    int* counts = (int*)alloc((N0 + N1 + N2) * 4);
    int* offs0 = (int*)alloc((N0 + 1) * 4);
    int* offs1 = (int*)alloc((N1 + 1) * 4);
    int* offs2 = (int*)alloc((N2 + 1) * 4);
    int* cur0 = (int*)alloc(N0 * 4);
    int* cur1 = (int*)alloc(N1 * 4);
    int* cur2 = (int*)alloc(N2 * 4);
    int* ss0 = (int*)alloc(E0C * 4);
    int* ss1 = (int*)alloc(E1C * 4);
    int* ss2 = (int*)alloc(E2C * 4);

    int etot = E0C + E1C + E2C;
    zero_ints<<<(N0 + N1 + N2 + 255) / 256, 256, 0, stream>>>(counts, N0 + N1 + N2);
    hist_all<<<(etot + 255) / 256, 256, 0, stream>>>(ei0, ei1, ei2, counts);
    scan_all<<<3, 1024, 0, stream>>>(counts, offs0, cur0, offs1, cur1, offs2, cur2);
    scatter_all<<<(etot + 255) / 256, 256, 0, stream>>>(ei0, ei1, ei2, cur0, cur1, cur2, ss0, ss1, ss2);
    gather_kernel<<<(N0 * 16 + 255) / 256, 256, 0, stream>>>(x, n_id, xt0p);
    sage1_kernel<<<N0 / 4, 256, 0, stream>>>(xt0p, offs0, ss0, W1, b1, xt1p);
    sage2_kernel<<<N0 / 4, 256, 0, stream>>>(xt1p, offs0, ss0, W2, b2, xt2);
    agg3_kernel<<<N1 / 4, 256, 0, stream>>>(xt2, offs1, ss1, aggT);
    matmul3_kernel<<<N1 / 4, 256, 0, stream>>>(aggT, W3, b3, W4, yb);
    final_kernel<<<(N2 * 16 + 255) / 256, 256, 0, stream>>>(yb, offs2, ss2, b4, out);
}

// Round 4
// 213.364 us; speedup vs baseline: 1.1346x; 1.1346x over previous
//
#include <hip/hip_runtime.h>
#include <hip/hip_fp16.h>

#define NTOT 50000
#define N0 20000
#define N1 5000
#define N2 1000
#define E0C 320000
#define E1C 80000
#define E2C 16000

__global__ void zero_ints(int* __restrict__ p, int n) {
    int i = blockIdx.x * blockDim.x + threadIdx.x;
    if (i < n) p[i] = 0;
}

// one fused histogram over all 3 graphs (counts: [0,N0)=g0, [N0,N0+N1)=g1, then g2)
__global__ void hist_all(const int* __restrict__ ei0, const int* __restrict__ ei1,
                         const int* __restrict__ ei2, int* __restrict__ counts) {
    int i = blockIdx.x * blockDim.x + threadIdx.x;
    if (i < E0C) {
        atomicAdd(&counts[ei0[E0C + i]], 1);
    } else if (i < E0C + E1C) {
        int j = i - E0C;
        atomicAdd(&counts[N0 + ei1[E1C + j]], 1);
    } else if (i < E0C + E1C + E2C) {
        int j = i - E0C - E1C;
        atomicAdd(&counts[N0 + N1 + ei2[E2C + j]], 1);
    }
}

// one block per graph; shuffle-based single-pass exclusive scan
__global__ __launch_bounds__(1024) void scan_all(
    const int* __restrict__ counts,
    int* __restrict__ offs0, int* __restrict__ cur0,
    int* __restrict__ offs1, int* __restrict__ cur1,
    int* __restrict__ offs2, int* __restrict__ cur2) {
    int g = blockIdx.x;
    int n = (g == 0) ? N0 : (g == 1) ? N1 : N2;
    const int* cnt = counts + ((g == 0) ? 0 : (g == 1) ? N0 : N0 + N1);
    int* offs = (g == 0) ? offs0 : (g == 1) ? offs1 : offs2;
    int* cur  = (g == 0) ? cur0  : (g == 1) ? cur1  : cur2;
    int t = threadIdx.x;
    int chunk = (n + 1023) >> 10;
    int lo = t * chunk;
    int hi = min(lo + chunk, n);
    int s = 0;
    for (int i = lo; i < hi; i++) s += cnt[i];
    int lane = t & 63, wid = t >> 6;
    int v = s;
    for (int d = 1; d < 64; d <<= 1) {
        int u = __shfl_up(v, d, 64);
        if (lane >= d) v += u;
    }
    __shared__ int wsum[16];
    __shared__ int woff[16];
    if (lane == 63) wsum[wid] = v;
    __syncthreads();
    if (t < 16) {
        int wv = wsum[t];
        int iv = wv;
        for (int d = 1; d < 16; d <<= 1) {
            int u = __shfl_up(iv, d, 64);
            if (t >= d) iv += u;
        }
        woff[t] = iv - wv;
    }
    __syncthreads();
    int run = woff[wid] + v - s;
    for (int i = lo; i < hi; i++) {
        offs[i] = run;
        cur[i] = run;
        run += cnt[i];
    }
    if (lo < n && hi == n) offs[n] = run;
}

__global__ void scatter_all(const int* __restrict__ ei0, const int* __restrict__ ei1,
                            const int* __restrict__ ei2,
                            int* __restrict__ cur0, int* __restrict__ cur1, int* __restrict__ cur2,
                            int* __restrict__ ss0, int* __restrict__ ss1, int* __restrict__ ss2) {
    int i = blockIdx.x * blockDim.x + threadIdx.x;
    if (i < E0C) {
        int d = ei0[E0C + i];
        int pos = atomicAdd(&cur0[d], 1);
        ss0[pos] = ei0[i];
    } else if (i < E0C + E1C) {
        int j = i - E0C;
        int d = ei1[E1C + j];
        int pos = atomicAdd(&cur1[d], 1);
        ss1[pos] = ei1[j];
    } else if (i < E0C + E1C + E2C) {
        int j = i - E0C - E1C;
        int d = ei2[E2C + j];
        int pos = atomicAdd(&cur2[d], 1);
        ss2[pos] = ei2[j];
    }
}

// xt0p[n][b][8] = x[b][n_id[n]][0..4] padded to 8 floats
__global__ void gather_kernel(const float* __restrict__ x, const int* __restrict__ n_id,
                              float* __restrict__ xt0p) {
    int idx = blockIdx.x * blockDim.x + threadIdx.x;
    if (idx >= N0 * 16) return;
    int n = idx >> 4, b = idx & 15;
    const float* p = x + (size_t)b * (NTOT * 5) + (size_t)n_id[n] * 5;
    float* q = xt0p + (size_t)n * 128 + b * 8;
    float4 v0 = {p[0], p[1], p[2], p[3]};
    float4 v1 = {p[4], 0.f, 0.f, 0.f};
    *(float4*)q = v0;
    *(float4*)(q + 4) = v1;
}

// SAGE layer 1: quarter-wave (16 lanes = batch) per dst node; fp32 in, fp16 out.
__global__ __launch_bounds__(256) void sage1_kernel(
    const float* __restrict__ xt0p, const int* __restrict__ offs, const int* __restrict__ ssrc,
    const float* __restrict__ W, const float* __restrict__ bias, __half* __restrict__ xt1h) {
    int gtid = blockIdx.x * blockDim.x + threadIdx.x;
    int wid = gtid >> 6;
    int lane = threadIdx.x & 63;
    int d = wid * 4 + (lane >> 4);
    int b = lane & 15;
    if (d >= N0) return;
    const float* ps = xt0p + (size_t)d * 128 + b * 8;
    float4 x0 = *(const float4*)ps;
    float x4 = ps[4];
    float xs[5] = {x0.x, x0.y, x0.z, x0.w, x4};
    float a[5] = {xs[0], xs[1], xs[2], xs[3], xs[4]};
    int e0 = offs[d], e1 = offs[d + 1];
    for (int e = e0; e < e1; e++) {
        int s = ssrc[e];
        const float* p = xt0p + (size_t)s * 128 + b * 8;
        float4 v = *(const float4*)p;
        float v4 = p[4];
        a[0] += v.x; a[1] += v.y; a[2] += v.z; a[3] += v.w; a[4] += v4;
    }
    float inv = 1.f / (float)(e1 - e0 + 1);
#pragma unroll
    for (int c = 0; c < 5; c++) a[c] *= inv;
    float o[6];
#pragma unroll
    for (int j = 0; j < 6; j++) {
        float acc = bias[j];
#pragma unroll
        for (int i = 0; i < 5; i++) acc += xs[i] * W[i * 6 + j];
#pragma unroll
        for (int i = 0; i < 5; i++) acc += a[i] * W[(5 + i) * 6 + j];
        o[j] = acc;
    }
    float nrm = 0.f;
#pragma unroll
    for (int j = 0; j < 6; j++) nrm += o[j] * o[j];
    float r = 1.f / fmaxf(sqrtf(nrm), 1e-12f);
    union { __half h[8]; uint4 u; } pk;
#pragma unroll
    for (int j = 0; j < 6; j++) pk.h[j] = __float2half_rn(fmaxf(o[j] * r, 0.f));
    pk.h[6] = __half(0.f);
    pk.h[7] = __half(0.f);
    *(uint4*)(xt1h + (size_t)d * 128 + b * 8) = pk.u;
}

// SAGE layer 2: quarter-wave per dst; fp16 in (single b128 gather/edge), fp32 out
__global__ __launch_bounds__(256) void sage2_kernel(
    const __half* __restrict__ xt1h, const int* __restrict__ offs, const int* __restrict__ ssrc,
    const float* __restrict__ W, const float* __restrict__ bias, float* __restrict__ xt2) {
    int gtid = blockIdx.x * blockDim.x + threadIdx.x;
    int wid = gtid >> 6;
    int lane = threadIdx.x & 63;
    int d = wid * 4 + (lane >> 4);
    int b = lane & 15;
    if (d >= N0) return;
    const __half2* ps = (const __half2*)(xt1h + (size_t)d * 128 + b * 8);
    float2 s01 = __half22float2(ps[0]);
    float2 s23 = __half22float2(ps[1]);
    float2 s45 = __half22float2(ps[2]);
    float xs[6] = {s01.x, s01.y, s23.x, s23.y, s45.x, s45.y};
    float a[6] = {xs[0], xs[1], xs[2], xs[3], xs[4], xs[5]};
    int e0 = offs[d], e1 = offs[d + 1];
    for (int e = e0; e < e1; e++) {
        int s = ssrc[e];
        uint4 raw = *(const uint4*)(xt1h + (size_t)s * 128 + b * 8);
        union { uint4 u; __half2 h2[4]; } pk;
        pk.u = raw;
        float2 v01 = __half22float2(pk.h2[0]);
        float2 v23 = __half22float2(pk.h2[1]);
        float2 v45 = __half22float2(pk.h2[2]);
        a[0] += v01.x; a[1] += v01.y; a[2] += v23.x;
        a[3] += v23.y; a[4] += v45.x; a[5] += v45.y;
    }
    float inv = 1.f / (float)(e1 - e0 + 1);
#pragma unroll
    for (int c = 0; c < 6; c++) a[c] *= inv;
    float o[36];
#pragma unroll
    for (int j = 0; j < 36; j++) {
        float acc = bias[j];
#pragma unroll
        for (int i = 0; i < 6; i++) acc += xs[i] * W[i * 36 + j];
#pragma unroll
        for (int i = 0; i < 6; i++) acc += a[i] * W[(6 + i) * 36 + j];
        o[j] = acc;
    }
    float nrm = 0.f;
#pragma unroll
    for (int j = 0; j < 36; j++) nrm += o[j] * o[j];
    float r = 1.f / fmaxf(sqrtf(nrm), 1e-12f);
    float* pd = xt2 + (size_t)d * 576 + b * 36;
#pragma unroll
    for (int j = 0; j < 9; j++) {
        float4 w = {fmaxf(o[4 * j] * r, 0.f), fmaxf(o[4 * j + 1] * r, 0.f),
                    fmaxf(o[4 * j + 2] * r, 0.f), fmaxf(o[4 * j + 3] * r, 0.f)};
        *(float4*)(pd + 4 * j) = w;
    }
}

// Fused layer-3: one 64-thread block per dst. Phase A: mean-agg into registers,
// transpose to a private 2.3KB LDS slice. Phase B: 16x216 matmul with agg from
// LDS broadcast (conflict-free) and W3 from global (L2-hot, 4-deep unrolled),
// then +b3, relu, W4 projection in-register. No 31KB LDS, no aggT round trip.
__global__ __launch_bounds__(64) void sage3_kernel(
    const float* __restrict__ xt2, const int* __restrict__ offs, const int* __restrict__ ssrc,
    const float* __restrict__ W3, const float* __restrict__ b3,
    const float* __restrict__ W4, float* __restrict__ y) {
    __shared__ float sT[576];   // [c][b] = agg transposed
    int q = threadIdx.x;
    int d = blockIdx.x;
    int e0 = offs[d], e1 = offs[d + 1];

    // phase A: mean aggregation (144 float4 chunks over 64 lanes), unroll 2
    float4 a0 = {0, 0, 0, 0}, a1 = {0, 0, 0, 0}, a2 = {0, 0, 0, 0};
    int e = e0;
    for (; e + 1 < e1; e += 2) {
        int s0 = ssrc[e], s1 = ssrc[e + 1];
        const float4* p0 = (const float4*)(xt2 + (size_t)s0 * 576);
        const float4* p1 = (const float4*)(xt2 + (size_t)s1 * 576);
        float4 v0 = p0[q], w0 = p1[q];
        float4 v1 = p0[q + 64], w1 = p1[q + 64];
        a0.x += v0.x + w0.x; a0.y += v0.y + w0.y; a0.z += v0.z + w0.z; a0.w += v0.w + w0.w;
        a1.x += v1.x + w1.x; a1.y += v1.y + w1.y; a1.z += v1.z + w1.z; a1.w += v1.w + w1.w;
        if (q < 16) {
            float4 v2 = p0[q + 128], w2 = p1[q + 128];
            a2.x += v2.x + w2.x; a2.y += v2.y + w2.y; a2.z += v2.z + w2.z; a2.w += v2.w + w2.w;
        }
    }
    if (e < e1) {
        int s0 = ssrc[e];
        const float4* p0 = (const float4*)(xt2 + (size_t)s0 * 576);
        float4 v0 = p0[q];
        float4 v1 = p0[q + 64];
        a0.x += v0.x; a0.y += v0.y; a0.z += v0.z; a0.w += v0.w;
        a1.x += v1.x; a1.y += v1.y; a1.z += v1.z; a1.w += v1.w;
        if (q < 16) {
            float4 v2 = p0[q + 128];
            a2.x += v2.x; a2.y += v2.y; a2.z += v2.z; a2.w += v2.w;
        }
    }
    float inv = 1.f / fmaxf((float)(e1 - e0), 1.f);
    float av[12] = {a0.x, a0.y, a0.z, a0.w, a1.x, a1.y, a1.z, a1.w, a2.x, a2.y, a2.z, a2.w};
#pragma unroll
    for (int m = 0; m < 3; m++) {
        int chunk = q + 64 * m;
        if (chunk < 144) {
#pragma unroll
            for (int j = 0; j < 4; j++) {
                int el = chunk * 4 + j;      // = b*36 + c
                int bb = el / 36;
                int cc = el - bb * 36;
                sT[cc * 16 + bb] = av[m * 4 + j] * inv;
            }
        }
    }
    __syncthreads();

    // phase B: agg(16x36) @ W3(36x216); thread = 4 cols (54 active lanes)
    int qc = (q < 54) ? q : 53;
    int o0 = qc * 4;
    float acc[16][4];
#pragma unroll
    for (int r = 0; r < 16; r++)
#pragma unroll
        for (int c = 0; c < 4; c++) acc[r][c] = 0.f;

#pragma unroll 4
    for (int k = 0; k < 36; k++) {
        float4 w = *(const float4*)&W3[k * 216 + o0];          // global, L2-hot
        const float4* sap = (const float4*)&sT[k * 16];        // LDS broadcast
        float4 s0 = sap[0], s1 = sap[1], s2 = sap[2], s3 = sap[3];
        float sar[16] = {s0.x, s0.y, s0.z, s0.w, s1.x, s1.y, s1.z, s1.w,
                         s2.x, s2.y, s2.z, s2.w, s3.x, s3.y, s3.z, s3.w};
#pragma unroll
        for (int r = 0; r < 16; r++) {
            acc[r][0] = fmaf(sar[r], w.x, acc[r][0]);
            acc[r][1] = fmaf(sar[r], w.y, acc[r][1]);
            acc[r][2] = fmaf(sar[r], w.z, acc[r][2]);
            acc[r][3] = fmaf(sar[r], w.w, acc[r][3]);
        }
    }

    // epilogue: +b3, relu, project by W4 (216->2) in-register
    float vals[32];
#pragma unroll
    for (int i = 0; i < 32; i++) vals[i] = 0.f;
    if (q < 54) {
        float4 bb = *(const float4*)&b3[o0];
        float4 w4a = *(const float4*)&W4[o0 * 2];
        float4 w4b = *(const float4*)&W4[o0 * 2 + 4];
        float w40[4] = {w4a.x, w4a.z, w4b.x, w4b.z};
        float w41[4] = {w4a.y, w4a.w, w4b.y, w4b.w};
        float bc[4] = {bb.x, bb.y, bb.z, bb.w};
#pragma unroll
        for (int r = 0; r < 16; r++) {
#pragma unroll
            for (int c = 0; c < 4; c++) {
                float vv = fmaxf(acc[r][c] + bc[c], 0.f);
                vals[r * 2 + 0] = fmaf(vv, w40[c], vals[r * 2 + 0]);
                vals[r * 2 + 1] = fmaf(vv, w41[c], vals[r * 2 + 1]);
            }
        }
    }
    // butterfly reduce-scatter over 64 lanes: 32 sums, each ends on one lane
#pragma unroll
    for (int i = 0; i < 5; i++) {
        int m = 1 << i;
        int half = 16 >> i;
        bool bit = (q >> i) & 1;
#pragma unroll
        for (int j = 0; j < 16; j++) {
            if (j < half) {
                float lo_ = vals[j], hi_ = vals[j + half];
                float send = bit ? lo_ : hi_;
                float recv = __shfl_xor(send, m, 64);
                vals[j] = (bit ? hi_ : lo_) + recv;
            }
        }
    }
    float tot = vals[0] + __shfl_xor(vals[0], 32, 64);
    if (q < 32) {
        int v = ((q & 1) << 4) | ((q & 2) << 2) | (q & 4) | ((q & 8) >> 2) | ((q & 16) >> 4);
        y[(size_t)d * 32 + v] = tot;   // v = b*2 + k
    }
}

// layer 4: mean-agg of projected y over edges2, + b4. out[b][n][k].
__global__ void final_kernel(const float* __restrict__ y, const int* __restrict__ offs,
                             const int* __restrict__ ssrc, const float* __restrict__ b4,
                             float* __restrict__ out) {
    int idx = blockIdx.x * blockDim.x + threadIdx.x;
    if (idx >= N2 * 16) return;
    int d = idx >> 4, b = idx & 15;
    int e0 = offs[d], e1 = offs[d + 1];
    float s0 = 0.f, s1 = 0.f;
    for (int e = e0; e < e1; e++) {
        int s = ssrc[e];
        const float2 v = *(const float2*)(y + (size_t)s * 32 + b * 2);
        s0 += v.x; s1 += v.y;
    }
    float inv = 1.f / fmaxf((float)(e1 - e0), 1.f);
    out[b * (N2 * 2) + d * 2 + 0] = s0 * inv + b4[0];
    out[b * (N2 * 2) + d * 2 + 1] = s1 * inv + b4[1];
}

extern "C" void kernel_launch(void* const* d_in, const int* in_sizes, int n_in,
                              void* d_out, int out_size, void* d_ws, size_t ws_size,
                              hipStream_t stream) {
    const float* x   = (const float*)d_in[0];
    const int* n_id  = (const int*)d_in[1];
    const int* ei0   = (const int*)d_in[2];
    const int* ei1   = (const int*)d_in[3];
    const int* ei2   = (const int*)d_in[4];
    const float* W1  = (const float*)d_in[5];
    const float* b1  = (const float*)d_in[6];
    const float* W2  = (const float*)d_in[7];
    const float* b2  = (const float*)d_in[8];
    const float* W3  = (const float*)d_in[9];
    const float* b3  = (const float*)d_in[10];
    const float* W4  = (const float*)d_in[11];
    const float* b4  = (const float*)d_in[12];
    float* out = (float*)d_out;

    char* ws = (char*)d_ws;
    size_t off = 0;
    auto alloc = [&](size_t bytes) -> void* {
        void* p = ws + off;
        off += (bytes + 255) & ~(size_t)255;
        return p;
    };
    float* xt0p  = (float*)alloc((size_t)N0 * 128 * 4);
    __half* xt1h = (__half*)alloc((size_t)N0 * 128 * 2);
    float* xt2   = (float*)alloc((size_t)N0 * 576 * 4);
    float* yb    = (float*)alloc((size_t)N1 * 32 * 4);
    int* counts = (int*)alloc((N0 + N1 + N2) * 4);
    int* offs0 = (int*)alloc((N0 + 1) * 4);
    int* offs1 = (int*)alloc((N1 + 1) * 4);
    int* offs2 = (int*)alloc((N2 + 1) * 4);
    int* cur0 = (int*)alloc(N0 * 4);
    int* cur1 = (int*)alloc(N1 * 4);
    int* cur2 = (int*)alloc(N2 * 4);
    int* ss0 = (int*)alloc(E0C * 4);
    int* ss1 = (int*)alloc(E1C * 4);
    int* ss2 = (int*)alloc(E2C * 4);

    int etot = E0C + E1C + E2C;
    zero_ints<<<(N0 + N1 + N2 + 255) / 256, 256, 0, stream>>>(counts, N0 + N1 + N2);
    hist_all<<<(etot + 255) / 256, 256, 0, stream>>>(ei0, ei1, ei2, counts);
    scan_all<<<3, 1024, 0, stream>>>(counts, offs0, cur0, offs1, cur1, offs2, cur2);
    scatter_all<<<(etot + 255) / 256, 256, 0, stream>>>(ei0, ei1, ei2, cur0, cur1, cur2, ss0, ss1, ss2);
    gather_kernel<<<(N0 * 16 + 255) / 256, 256, 0, stream>>>(x, n_id, xt0p);
    sage1_kernel<<<N0 / 16, 256, 0, stream>>>(xt0p, offs0, ss0, W1, b1, xt1h);
    sage2_kernel<<<N0 / 16, 256, 0, stream>>>(xt1h, offs0, ss0, W2, b2, xt2);
    sage3_kernel<<<N1, 64, 0, stream>>>(xt2, offs1, ss1, W3, b3, W4, yb);
    final_kernel<<<(N2 * 16 + 255) / 256, 256, 0, stream>>>(yb, offs2, ss2, b4, out);
}

// Round 5
// 202.929 us; speedup vs baseline: 1.1929x; 1.0514x over previous
//
#include <hip/hip_runtime.h>
#include <hip/hip_fp16.h>

#define NTOT 50000
#define N0 20000
#define N1 5000
#define N2 1000
#define E0C 320000
#define E1C 80000
#define E2C 16000

__global__ void zero_ints(int* __restrict__ p, int n) {
    int i = blockIdx.x * blockDim.x + threadIdx.x;
    if (i < n) p[i] = 0;
}

__global__ void hist_all(const int* __restrict__ ei0, const int* __restrict__ ei1,
                         const int* __restrict__ ei2, int* __restrict__ counts) {
    int i = blockIdx.x * blockDim.x + threadIdx.x;
    if (i < E0C) {
        atomicAdd(&counts[ei0[E0C + i]], 1);
    } else if (i < E0C + E1C) {
        int j = i - E0C;
        atomicAdd(&counts[N0 + ei1[E1C + j]], 1);
    } else if (i < E0C + E1C + E2C) {
        int j = i - E0C - E1C;
        atomicAdd(&counts[N0 + N1 + ei2[E2C + j]], 1);
    }
}

__global__ __launch_bounds__(1024) void scan_all(
    const int* __restrict__ counts,
    int* __restrict__ offs0, int* __restrict__ cur0,
    int* __restrict__ offs1, int* __restrict__ cur1,
    int* __restrict__ offs2, int* __restrict__ cur2) {
    int g = blockIdx.x;
    int n = (g == 0) ? N0 : (g == 1) ? N1 : N2;
    const int* cnt = counts + ((g == 0) ? 0 : (g == 1) ? N0 : N0 + N1);
    int* offs = (g == 0) ? offs0 : (g == 1) ? offs1 : offs2;
    int* cur  = (g == 0) ? cur0  : (g == 1) ? cur1  : cur2;
    int t = threadIdx.x;
    int chunk = (n + 1023) >> 10;
    int lo = t * chunk;
    int hi = min(lo + chunk, n);
    int s = 0;
    for (int i = lo; i < hi; i++) s += cnt[i];
    int lane = t & 63, wid = t >> 6;
    int v = s;
    for (int d = 1; d < 64; d <<= 1) {
        int u = __shfl_up(v, d, 64);
        if (lane >= d) v += u;
    }
    __shared__ int wsum[16];
    __shared__ int woff[16];
    if (lane == 63) wsum[wid] = v;
    __syncthreads();
    if (t < 16) {
        int wv = wsum[t];
        int iv = wv;
        for (int d = 1; d < 16; d <<= 1) {
            int u = __shfl_up(iv, d, 64);
            if (t >= d) iv += u;
        }
        woff[t] = iv - wv;
    }
    __syncthreads();
    int run = woff[wid] + v - s;
    for (int i = lo; i < hi; i++) {
        offs[i] = run;
        cur[i] = run;
        run += cnt[i];
    }
    if (lo < n && hi == n) offs[n] = run;
}

__global__ void scatter_all(const int* __restrict__ ei0, const int* __restrict__ ei1,
                            const int* __restrict__ ei2,
                            int* __restrict__ cur0, int* __restrict__ cur1, int* __restrict__ cur2,
                            int* __restrict__ ss0, int* __restrict__ ss1, int* __restrict__ ss2) {
    int i = blockIdx.x * blockDim.x + threadIdx.x;
    if (i < E0C) {
        int d = ei0[E0C + i];
        int pos = atomicAdd(&cur0[d], 1);
        ss0[pos] = ei0[i];
    } else if (i < E0C + E1C) {
        int j = i - E0C;
        int d = ei1[E1C + j];
        int pos = atomicAdd(&cur1[d], 1);
        ss1[pos] = ei1[j];
    } else if (i < E0C + E1C + E2C) {
        int j = i - E0C - E1C;
        int d = ei2[E2C + j];
        int pos = atomicAdd(&cur2[d], 1);
        ss2[pos] = ei2[j];
    }
}

// xt0p[n][b][8] = x[b][n_id[n]][0..4] padded to 8 floats
__global__ void gather_kernel(const float* __restrict__ x, const int* __restrict__ n_id,
                              float* __restrict__ xt0p) {
    int idx = blockIdx.x * blockDim.x + threadIdx.x;
    if (idx >= N0 * 16) return;
    int n = idx >> 4, b = idx & 15;
    const float* p = x + (size_t)b * (NTOT * 5) + (size_t)n_id[n] * 5;
    float* q = xt0p + (size_t)n * 128 + b * 8;
    float4 v0 = {p[0], p[1], p[2], p[3]};
    float4 v1 = {p[4], 0.f, 0.f, 0.f};
    *(float4*)q = v0;
    *(float4*)(q + 4) = v1;
}

// SAGE layer 1: quarter-wave per dst; fp32 in, fp16 out; edge loop unrolled x2
__global__ __launch_bounds__(256) void sage1_kernel(
    const float* __restrict__ xt0p, const int* __restrict__ offs, const int* __restrict__ ssrc,
    const float* __restrict__ W, const float* __restrict__ bias, __half* __restrict__ xt1h) {
    int gtid = blockIdx.x * blockDim.x + threadIdx.x;
    int wid = gtid >> 6;
    int lane = threadIdx.x & 63;
    int d = wid * 4 + (lane >> 4);
    int b = lane & 15;
    if (d >= N0) return;
    const float* ps = xt0p + (size_t)d * 128 + b * 8;
    float4 x0 = *(const float4*)ps;
    float x4 = ps[4];
    float xs[5] = {x0.x, x0.y, x0.z, x0.w, x4};
    float a[5] = {xs[0], xs[1], xs[2], xs[3], xs[4]};
    int e0 = offs[d], e1 = offs[d + 1];
    int e = e0;
    for (; e + 1 < e1; e += 2) {
        int s0 = ssrc[e], s1 = ssrc[e + 1];
        const float* p0 = xt0p + (size_t)s0 * 128 + b * 8;
        const float* p1 = xt0p + (size_t)s1 * 128 + b * 8;
        float4 v = *(const float4*)p0;
        float v4 = p0[4];
        float4 w = *(const float4*)p1;
        float w4 = p1[4];
        a[0] += v.x + w.x; a[1] += v.y + w.y; a[2] += v.z + w.z;
        a[3] += v.w + w.w; a[4] += v4 + w4;
    }
    if (e < e1) {
        const float* p = xt0p + (size_t)ssrc[e] * 128 + b * 8;
        float4 v = *(const float4*)p;
        float v4 = p[4];
        a[0] += v.x; a[1] += v.y; a[2] += v.z; a[3] += v.w; a[4] += v4;
    }
    float inv = 1.f / (float)(e1 - e0 + 1);
#pragma unroll
    for (int c = 0; c < 5; c++) a[c] *= inv;
    float o[6];
#pragma unroll
    for (int j = 0; j < 6; j++) {
        float acc = bias[j];
#pragma unroll
        for (int i = 0; i < 5; i++) acc += xs[i] * W[i * 6 + j];
#pragma unroll
        for (int i = 0; i < 5; i++) acc += a[i] * W[(5 + i) * 6 + j];
        o[j] = acc;
    }
    float nrm = 0.f;
#pragma unroll
    for (int j = 0; j < 6; j++) nrm += o[j] * o[j];
    float r = 1.f / fmaxf(sqrtf(nrm), 1e-12f);
    union { __half h[8]; uint4 u; } pk;
#pragma unroll
    for (int j = 0; j < 6; j++) pk.h[j] = __float2half_rn(fmaxf(o[j] * r, 0.f));
    pk.h[6] = __half(0.f);
    pk.h[7] = __half(0.f);
    *(uint4*)(xt1h + (size_t)d * 128 + b * 8) = pk.u;
}

// SAGE layer 2: quarter-wave per dst; fp16 in (1 b128/edge, unroll x2),
// writes xt2h TRANSPOSED fp16: xt2h[d][c][b] (c<36, b<16)
__global__ __launch_bounds__(256) void sage2_kernel(
    const __half* __restrict__ xt1h, const int* __restrict__ offs, const int* __restrict__ ssrc,
    const float* __restrict__ W, const float* __restrict__ bias, __half* __restrict__ xt2h) {
    int gtid = blockIdx.x * blockDim.x + threadIdx.x;
    int wid = gtid >> 6;
    int lane = threadIdx.x & 63;
    int d = wid * 4 + (lane >> 4);
    int b = lane & 15;
    if (d >= N0) return;
    const __half2* ps = (const __half2*)(xt1h + (size_t)d * 128 + b * 8);
    float2 s01 = __half22float2(ps[0]);
    float2 s23 = __half22float2(ps[1]);
    float2 s45 = __half22float2(ps[2]);
    float xs[6] = {s01.x, s01.y, s23.x, s23.y, s45.x, s45.y};
    float a[6] = {xs[0], xs[1], xs[2], xs[3], xs[4], xs[5]};
    int e0 = offs[d], e1 = offs[d + 1];
    int e = e0;
    union { uint4 u; __half2 h2[4]; } pk0, pk1;
    for (; e + 1 < e1; e += 2) {
        int s0 = ssrc[e], s1 = ssrc[e + 1];
        pk0.u = *(const uint4*)(xt1h + (size_t)s0 * 128 + b * 8);
        pk1.u = *(const uint4*)(xt1h + (size_t)s1 * 128 + b * 8);
        float2 v01 = __half22float2(pk0.h2[0]);
        float2 v23 = __half22float2(pk0.h2[1]);
        float2 v45 = __half22float2(pk0.h2[2]);
        float2 w01 = __half22float2(pk1.h2[0]);
        float2 w23 = __half22float2(pk1.h2[1]);
        float2 w45 = __half22float2(pk1.h2[2]);
        a[0] += v01.x + w01.x; a[1] += v01.y + w01.y; a[2] += v23.x + w23.x;
        a[3] += v23.y + w23.y; a[4] += v45.x + w45.x; a[5] += v45.y + w45.y;
    }
    if (e < e1) {
        pk0.u = *(const uint4*)(xt1h + (size_t)ssrc[e] * 128 + b * 8);
        float2 v01 = __half22float2(pk0.h2[0]);
        float2 v23 = __half22float2(pk0.h2[1]);
        float2 v45 = __half22float2(pk0.h2[2]);
        a[0] += v01.x; a[1] += v01.y; a[2] += v23.x;
        a[3] += v23.y; a[4] += v45.x; a[5] += v45.y;
    }
    float inv = 1.f / (float)(e1 - e0 + 1);
#pragma unroll
    for (int c = 0; c < 6; c++) a[c] *= inv;
    float o[36];
#pragma unroll
    for (int j = 0; j < 36; j++) {
        float acc = bias[j];
#pragma unroll
        for (int i = 0; i < 6; i++) acc += xs[i] * W[i * 36 + j];
#pragma unroll
        for (int i = 0; i < 6; i++) acc += a[i] * W[(6 + i) * 36 + j];
        o[j] = acc;
    }
    float nrm = 0.f;
#pragma unroll
    for (int j = 0; j < 36; j++) nrm += o[j] * o[j];
    float r = 1.f / fmaxf(sqrtf(nrm), 1e-12f);
    __half* pd = xt2h + (size_t)d * 576 + b;   // [d][c][b] layout, stride 16 per c
#pragma unroll
    for (int j = 0; j < 36; j++) pd[j * 16] = __float2half_rn(fmaxf(o[j] * r, 0.f));
}

// Fused layer-3: 256-thread block = 4 independent waves, wave per dst.
// Phase A: mean-agg of fp16 [c][b] rows (72 uint4/edge, coalesced, unroll x2)
// into fp32 regs -> private LDS slice (no transpose math needed).
// Phase B: 16x216 matmul, agg via LDS broadcast, W3 from global (L2-hot),
// +b3, relu, W4 projection in-register, butterfly reduce, store y.
__global__ __launch_bounds__(256) void sage3_kernel(
    const __half* __restrict__ xt2h, const int* __restrict__ offs, const int* __restrict__ ssrc,
    const float* __restrict__ W3, const float* __restrict__ b3,
    const float* __restrict__ W4, float* __restrict__ y) {
    __shared__ float sT[4][576];
    int t = threadIdx.x;
    int l = t >> 6, q = t & 63;
    int d = blockIdx.x * 4 + l;
    int e0 = offs[d], e1 = offs[d + 1];

    float acc[16];
#pragma unroll
    for (int i = 0; i < 16; i++) acc[i] = 0.f;
    const uint4* base = (const uint4*)xt2h;   // node row = 72 uint4 (1152B)
    union { uint4 u; __half2 h2[4]; } c0, c1, x0, x1;
    int e = e0;
    for (; e + 1 < e1; e += 2) {
        const uint4* p0 = base + (size_t)ssrc[e] * 72;
        const uint4* p1 = base + (size_t)ssrc[e + 1] * 72;
        c0.u = p0[q];
        c1.u = p1[q];
#pragma unroll
        for (int j = 0; j < 4; j++) {
            float2 f0 = __half22float2(c0.h2[j]);
            float2 f1 = __half22float2(c1.h2[j]);
            acc[2 * j] += f0.x + f1.x;
            acc[2 * j + 1] += f0.y + f1.y;
        }
        if (q < 8) {
            x0.u = p0[64 + q];
            x1.u = p1[64 + q];
#pragma unroll
            for (int j = 0; j < 4; j++) {
                float2 f0 = __half22float2(x0.h2[j]);
                float2 f1 = __half22float2(x1.h2[j]);
                acc[8 + 2 * j] += f0.x + f1.x;
                acc[9 + 2 * j] += f0.y + f1.y;
            }
        }
    }
    if (e < e1) {
        const uint4* p0 = base + (size_t)ssrc[e] * 72;
        c0.u = p0[q];
#pragma unroll
        for (int j = 0; j < 4; j++) {
            float2 f0 = __half22float2(c0.h2[j]);
            acc[2 * j] += f0.x;
            acc[2 * j + 1] += f0.y;
        }
        if (q < 8) {
            x0.u = p0[64 + q];
#pragma unroll
            for (int j = 0; j < 4; j++) {
                float2 f0 = __half22float2(x0.h2[j]);
                acc[8 + 2 * j] += f0.x;
                acc[9 + 2 * j] += f0.y;
            }
        }
    }
    float inv = 1.f / fmaxf((float)(e1 - e0), 1.f);
#pragma unroll
    for (int j = 0; j < 8; j++) sT[l][q * 8 + j] = acc[j] * inv;
    if (q < 8) {
#pragma unroll
        for (int j = 0; j < 8; j++) sT[l][512 + q * 8 + j] = acc[8 + j] * inv;
    }
    __syncthreads();

    // phase B
    int qc = (q < 54) ? q : 53;
    int o0 = qc * 4;
    float macc[16][4];
#pragma unroll
    for (int r = 0; r < 16; r++)
#pragma unroll
        for (int c = 0; c < 4; c++) macc[r][c] = 0.f;

#pragma unroll 4
    for (int k = 0; k < 36; k++) {
        float4 w = *(const float4*)&W3[k * 216 + o0];          // global, L2-hot
        const float4* sap = (const float4*)&sT[l][k * 16];     // LDS broadcast
        float4 s0 = sap[0], s1 = sap[1], s2 = sap[2], s3 = sap[3];
        float sar[16] = {s0.x, s0.y, s0.z, s0.w, s1.x, s1.y, s1.z, s1.w,
                         s2.x, s2.y, s2.z, s2.w, s3.x, s3.y, s3.z, s3.w};
#pragma unroll
        for (int r = 0; r < 16; r++) {
            macc[r][0] = fmaf(sar[r], w.x, macc[r][0]);
            macc[r][1] = fmaf(sar[r], w.y, macc[r][1]);
            macc[r][2] = fmaf(sar[r], w.z, macc[r][2]);
            macc[r][3] = fmaf(sar[r], w.w, macc[r][3]);
        }
    }

    float vals[32];
#pragma unroll
    for (int i = 0; i < 32; i++) vals[i] = 0.f;
    if (q < 54) {
        float4 bb = *(const float4*)&b3[o0];
        float4 w4a = *(const float4*)&W4[o0 * 2];
        float4 w4b = *(const float4*)&W4[o0 * 2 + 4];
        float w40[4] = {w4a.x, w4a.z, w4b.x, w4b.z};
        float w41[4] = {w4a.y, w4a.w, w4b.y, w4b.w};
        float bc[4] = {bb.x, bb.y, bb.z, bb.w};
#pragma unroll
        for (int r = 0; r < 16; r++) {
#pragma unroll
            for (int c = 0; c < 4; c++) {
                float vv = fmaxf(macc[r][c] + bc[c], 0.f);
                vals[r * 2 + 0] = fmaf(vv, w40[c], vals[r * 2 + 0]);
                vals[r * 2 + 1] = fmaf(vv, w41[c], vals[r * 2 + 1]);
            }
        }
    }
#pragma unroll
    for (int i = 0; i < 5; i++) {
        int m = 1 << i;
        int half = 16 >> i;
        bool bit = (q >> i) & 1;
#pragma unroll
        for (int j = 0; j < 16; j++) {
            if (j < half) {
                float lo_ = vals[j], hi_ = vals[j + half];
                float send = bit ? lo_ : hi_;
                float recv = __shfl_xor(send, m, 64);
                vals[j] = (bit ? hi_ : lo_) + recv;
            }
        }
    }
    float tot = vals[0] + __shfl_xor(vals[0], 32, 64);
    if (q < 32) {
        int v = ((q & 1) << 4) | ((q & 2) << 2) | (q & 4) | ((q & 8) >> 2) | ((q & 16) >> 4);
        y[(size_t)d * 32 + v] = tot;   // v = b*2 + k
    }
}

// layer 4: mean-agg of projected y over edges2, + b4. out[b][n][k].
__global__ void final_kernel(const float* __restrict__ y, const int* __restrict__ offs,
                             const int* __restrict__ ssrc, const float* __restrict__ b4,
                             float* __restrict__ out) {
    int idx = blockIdx.x * blockDim.x + threadIdx.x;
    if (idx >= N2 * 16) return;
    int d = idx >> 4, b = idx & 15;
    int e0 = offs[d], e1 = offs[d + 1];
    float s0 = 0.f, s1 = 0.f;
    for (int e = e0; e < e1; e++) {
        int s = ssrc[e];
        const float2 v = *(const float2*)(y + (size_t)s * 32 + b * 2);
        s0 += v.x; s1 += v.y;
    }
    float inv = 1.f / fmaxf((float)(e1 - e0), 1.f);
    out[b * (N2 * 2) + d * 2 + 0] = s0 * inv + b4[0];
    out[b * (N2 * 2) + d * 2 + 1] = s1 * inv + b4[1];
}

extern "C" void kernel_launch(void* const* d_in, const int* in_sizes, int n_in,
                              void* d_out, int out_size, void* d_ws, size_t ws_size,
                              hipStream_t stream) {
    const float* x   = (const float*)d_in[0];
    const int* n_id  = (const int*)d_in[1];
    const int* ei0   = (const int*)d_in[2];
    const int* ei1   = (const int*)d_in[3];
    const int* ei2   = (const int*)d_in[4];
    const float* W1  = (const float*)d_in[5];
    const float* b1  = (const float*)d_in[6];
    const float* W2  = (const float*)d_in[7];
    const float* b2  = (const float*)d_in[8];
    const float* W3  = (const float*)d_in[9];
    const float* b3  = (const float*)d_in[10];
    const float* W4  = (const float*)d_in[11];
    const float* b4  = (const float*)d_in[12];
    float* out = (float*)d_out;

    char* ws = (char*)d_ws;
    size_t off = 0;
    auto alloc = [&](size_t bytes) -> void* {
        void* p = ws + off;
        off += (bytes + 255) & ~(size_t)255;
        return p;
    };
    float* xt0p  = (float*)alloc((size_t)N0 * 128 * 4);
    __half* xt1h = (__half*)alloc((size_t)N0 * 128 * 2);
    __half* xt2h = (__half*)alloc((size_t)N0 * 576 * 2);
    float* yb    = (float*)alloc((size_t)N1 * 32 * 4);
    int* counts = (int*)alloc((N0 + N1 + N2) * 4);
    int* offs0 = (int*)alloc((N0 + 1) * 4);
    int* offs1 = (int*)alloc((N1 + 1) * 4);
    int* offs2 = (int*)alloc((N2 + 1) * 4);
    int* cur0 = (int*)alloc(N0 * 4);
    int* cur1 = (int*)alloc(N1 * 4);
    int* cur2 = (int*)alloc(N2 * 4);
    int* ss0 = (int*)alloc(E0C * 4);
    int* ss1 = (int*)alloc(E1C * 4);
    int* ss2 = (int*)alloc(E2C * 4);

    int etot = E0C + E1C + E2C;
    zero_ints<<<(N0 + N1 + N2 + 255) / 256, 256, 0, stream>>>(counts, N0 + N1 + N2);
    hist_all<<<(etot + 255) / 256, 256, 0, stream>>>(ei0, ei1, ei2, counts);
    scan_all<<<3, 1024, 0, stream>>>(counts, offs0, cur0, offs1, cur1, offs2, cur2);
    scatter_all<<<(etot + 255) / 256, 256, 0, stream>>>(ei0, ei1, ei2, cur0, cur1, cur2, ss0, ss1, ss2);
    gather_kernel<<<(N0 * 16 + 255) / 256, 256, 0, stream>>>(x, n_id, xt0p);
    sage1_kernel<<<N0 / 16, 256, 0, stream>>>(xt0p, offs0, ss0, W1, b1, xt1h);
    sage2_kernel<<<N0 / 16, 256, 0, stream>>>(xt1h, offs0, ss0, W2, b2, xt2h);
    sage3_kernel<<<N1 / 4, 256, 0, stream>>>(xt2h, offs1, ss1, W3, b3, W4, yb);
    final_kernel<<<(N2 * 16 + 255) / 256, 256, 0, stream>>>(yb, offs2, ss2, b4, out);
}